// Round 11
// baseline (487.627 us; speedup 1.0000x reference)
//
#include <hip/hip_runtime.h>

typedef unsigned short u16;
typedef short short8 __attribute__((ext_vector_type(8)));
typedef unsigned short ushort8 __attribute__((ext_vector_type(8)));
typedef unsigned short bf16x4 __attribute__((ext_vector_type(4)));
typedef float f32x4 __attribute__((ext_vector_type(4)));

#define DEVINL __device__ __forceinline__

DEVINL float bf2f(u16 u) {
  unsigned int x = ((unsigned int)u) << 16;
  return __builtin_bit_cast(float, x);
}
DEVINL u16 f2bf(float f) {
  unsigned int x = __builtin_bit_cast(unsigned int, f);
  x += 0x7FFFu + ((x >> 16) & 1u);  // RNE
  return (u16)(x >> 16);
}

// Problem constants: B=2, S=2048, E=1024, H=16, DH=64
// Inputs float32; big operands converted once to bf16; MFMA internally;
// final output written as float32.
// Schedule note (round 11): scores->conv are interleaved in q-stripes of 1024
// so the raw-score stripe written by the scores GEMM is still L3-resident when
// conv reads it, and P accumulates in L3 for the PV GEMM (live set ~198 MB
// < 256 MB Infinity Cache; the un-striped version thrashed at ~268 MB).

// ---------------------------------------------------------------------------
// Fused f32 -> bf16 conversion of query + 4 weight matrices.
// ---------------------------------------------------------------------------
__global__ __launch_bounds__(256) void cvt_all(
    const float* __restrict__ q, const float* __restrict__ wq,
    const float* __restrict__ wk, const float* __restrict__ wv,
    const float* __restrict__ wo, u16* __restrict__ out) {
  int i = blockIdx.x * 256 + threadIdx.x;  // < 1048576
  const float* src;
  size_t off8;
  if (i < 524288) { src = q;  off8 = i; }
  else if (i < 655360) { src = wq; off8 = i - 524288; }
  else if (i < 786432) { src = wk; off8 = i - 655360; }
  else if (i < 917504) { src = wv; off8 = i - 786432; }
  else { src = wo; off8 = i - 917504; }
  f32x4 a = ((const f32x4*)src)[2 * off8];
  f32x4 b = ((const f32x4*)src)[2 * off8 + 1];
  ushort8 o;
#pragma unroll
  for (int e = 0; e < 4; ++e) o[e] = f2bf(a[e]);
#pragma unroll
  for (int e = 0; e < 4; ++e) o[4 + e] = f2bf(b[e]);
  ((ushort8*)out)[i] = o;
}

// ---------------------------------------------------------------------------
// NT GEMM (bf16 in via MFMA): C[i,j] = scale * sum_k A[i,k]*B[j,k] (+ bias[j])
// BK: K-tile (32 or 64). RSCALE: multiply row i of batch z by rsc[z*2048+i].
// rsOff: global row offset for RSCALE indexing (q-stripe support).
// ---------------------------------------------------------------------------
template <int BM, int BN, int BK, bool TRANSV, bool HASBIAS, bool OUTF32,
          bool RSCALE>
__global__ __launch_bounds__(256) void gemm_nt(
    const u16* __restrict__ A, const u16* __restrict__ Bm,
    const float* __restrict__ bias, void* __restrict__ C,
    const float* __restrict__ rsc,
    int K, int lda, int ldb, int ldc, float scale,
    long long sAh, long long sBh, long long sCh) {
  constexpr int LDSS = BK + 8;       // padded LDS row stride (u16)
  constexpr int KC8 = BK / 8;        // 8-elem groups per row
  constexpr int KSH = (BK == 32) ? 2 : 3;
  constexpr int WM = BM / 2, WN = BN / 2, FM = WM / 16, FN = WN / 16;
  constexpr int AIN = BM * KC8 / 256;
  constexpr int BIN = BN * KC8 / 256;

  __shared__ alignas(16) u16 As[BM * LDSS];
  __shared__ alignas(16) u16 Bs[BN * LDSS];

  const int tid = threadIdx.x;
  const int lane = tid & 63;
  const int wv = tid >> 6;
  const int wy = wv >> 1, wx = wv & 1;
  const int quad = lane >> 4, mrow = lane & 15;

  const int z = blockIdx.z;
  const u16* Ap = A + z * sAh;
  const u16* Bp = Bm + z * sBh;
  u16* Cp = (u16*)C + z * sCh;
  float* Cf = (float*)C + z * sCh;

  const int row0 = blockIdx.y * BM;
  const int col0 = blockIdx.x * BN;

  f32x4 acc[FM][FN];
#pragma unroll
  for (int i = 0; i < FM; ++i)
#pragma unroll
    for (int j = 0; j < FN; ++j) acc[i][j] = f32x4{0.f, 0.f, 0.f, 0.f};

  for (int k0 = 0; k0 < K; k0 += BK) {
    ushort8 ta[AIN], tb[BIN];
#pragma unroll
    for (int r = 0; r < AIN; ++r) {
      int idx = r * 256 + tid;
      int row = idx >> KSH, ch = idx & (KC8 - 1);
      ta[r] = *(const ushort8*)(Ap + (size_t)(row0 + row) * lda + k0 + ch * 8);
    }
#pragma unroll
    for (int r = 0; r < BIN; ++r) {
      int idx = r * 256 + tid;
      int row = idx >> KSH, ch = idx & (KC8 - 1);
      tb[r] = *(const ushort8*)(Bp + (size_t)(col0 + row) * ldb + k0 + ch * 8);
    }
    __syncthreads();  // previous iteration's LDS reads done
#pragma unroll
    for (int r = 0; r < AIN; ++r) {
      int idx = r * 256 + tid;
      int row = idx >> KSH, ch = idx & (KC8 - 1);
      *(ushort8*)&As[row * LDSS + ch * 8] = ta[r];
    }
#pragma unroll
    for (int r = 0; r < BIN; ++r) {
      int idx = r * 256 + tid;
      int row = idx >> KSH, ch = idx & (KC8 - 1);
      *(ushort8*)&Bs[row * LDSS + ch * 8] = tb[r];
    }
    __syncthreads();

#pragma unroll
    for (int ks = 0; ks < BK / 32; ++ks) {
      short8 af[FM], bfr[FN];
#pragma unroll
      for (int mi = 0; mi < FM; ++mi)
        af[mi] = *(const short8*)&As[(wy * WM + mi * 16 + mrow) * LDSS + ks * 32 + quad * 8];
#pragma unroll
      for (int ni = 0; ni < FN; ++ni)
        bfr[ni] = *(const short8*)&Bs[(wx * WN + ni * 16 + mrow) * LDSS + ks * 32 + quad * 8];
#pragma unroll
      for (int mi = 0; mi < FM; ++mi)
#pragma unroll
        for (int ni = 0; ni < FN; ++ni)
          acc[mi][ni] = __builtin_amdgcn_mfma_f32_16x16x32_bf16(
              af[mi], bfr[ni], acc[mi][ni], 0, 0, 0);
    }
  }

  // Epilogue. C/D layout: col = lane&15, row = quad*4 + r  [m89/m91 verified]
#pragma unroll
  for (int mi = 0; mi < FM; ++mi) {
    const int rowb = row0 + wy * WM + mi * 16 + quad * 4;
#pragma unroll
    for (int ni = 0; ni < FN; ++ni) {
      const int col = col0 + wx * WN + ni * 16 + mrow;
      float bv = 0.f;
      if (HASBIAS) bv = bias[col];
      f32x4 v = acc[mi][ni];
      if (OUTF32) {
#pragma unroll
        for (int r = 0; r < 4; ++r)
          Cf[(size_t)(rowb + r) * ldc + col] = v[r] * scale + bv;
      } else if (!TRANSV) {
#pragma unroll
        for (int r = 0; r < 4; ++r) {
          float rs = 1.f;
          if (RSCALE) rs = rsc[(size_t)z * 2048 + rowb + r];
          Cp[(size_t)(rowb + r) * ldc + col] = f2bf(v[r] * scale * rs + bv);
        }
      } else {
        // Ct[b][col][s], per-batch stride E*S = 2097152
        const int bb = rowb >> 11;
        const int ss = rowb & 2047;
        bf16x4 pk;
#pragma unroll
        for (int r = 0; r < 4; ++r) pk[r] = f2bf(v[r] * scale + bv);
        *(bf16x4*)(Cp + (size_t)bb * 2097152 + (size_t)col * 2048 + ss) = pk;
      }
    }
  }
}

// ---------------------------------------------------------------------------
// Fused QKV projection: A = Qb [4096 x 1024], B = Wq|Wk|Wv rows [3072 x 1024].
// col part (block-uniform, BN=128): 0 -> Qw, 1 -> Kw, 2 -> Vt (transposed
// store Vt[b][e][s]). BK=32, BM=BN=128.
// ---------------------------------------------------------------------------
__global__ __launch_bounds__(256) void gemm_qkv(
    const u16* __restrict__ A, const u16* __restrict__ Bm,
    const float* __restrict__ bq, const float* __restrict__ bk,
    const float* __restrict__ bv,
    u16* __restrict__ Qw, u16* __restrict__ Kw, u16* __restrict__ Vt) {
  constexpr int LDSS = 40;
  __shared__ alignas(16) u16 As[128 * LDSS];
  __shared__ alignas(16) u16 Bs[128 * LDSS];

  const int tid = threadIdx.x;
  const int lane = tid & 63;
  const int wv = tid >> 6;
  const int wy = wv >> 1, wx = wv & 1;
  const int quad = lane >> 4, mrow = lane & 15;

  const int row0 = blockIdx.y * 128;
  const int col0 = blockIdx.x * 128;

  f32x4 acc[4][4];
#pragma unroll
  for (int i = 0; i < 4; ++i)
#pragma unroll
    for (int j = 0; j < 4; ++j) acc[i][j] = f32x4{0.f, 0.f, 0.f, 0.f};

  for (int k0 = 0; k0 < 1024; k0 += 32) {
    ushort8 ta[2], tb[2];
#pragma unroll
    for (int r = 0; r < 2; ++r) {
      int idx = r * 256 + tid;
      int row = idx >> 2, ch = idx & 3;
      ta[r] = *(const ushort8*)(A + (size_t)(row0 + row) * 1024 + k0 + ch * 8);
      tb[r] = *(const ushort8*)(Bm + (size_t)(col0 + row) * 1024 + k0 + ch * 8);
    }
    __syncthreads();
#pragma unroll
    for (int r = 0; r < 2; ++r) {
      int idx = r * 256 + tid;
      int row = idx >> 2, ch = idx & 3;
      *(ushort8*)&As[row * LDSS + ch * 8] = ta[r];
      *(ushort8*)&Bs[row * LDSS + ch * 8] = tb[r];
    }
    __syncthreads();

    short8 af[4], bfr[4];
#pragma unroll
    for (int mi = 0; mi < 4; ++mi)
      af[mi] = *(const short8*)&As[(wy * 64 + mi * 16 + mrow) * LDSS + quad * 8];
#pragma unroll
    for (int ni = 0; ni < 4; ++ni)
      bfr[ni] = *(const short8*)&Bs[(wx * 64 + ni * 16 + mrow) * LDSS + quad * 8];
#pragma unroll
    for (int mi = 0; mi < 4; ++mi)
#pragma unroll
      for (int ni = 0; ni < 4; ++ni)
        acc[mi][ni] = __builtin_amdgcn_mfma_f32_16x16x32_bf16(
            af[mi], bfr[ni], acc[mi][ni], 0, 0, 0);
  }

  const int part = col0 >> 10;  // 0:Q 1:K 2:V (block-uniform)
  const float* bias = (part == 0) ? bq : (part == 1) ? bk : bv;
#pragma unroll
  for (int mi = 0; mi < 4; ++mi) {
    const int rowb = row0 + wy * 64 + mi * 16 + quad * 4;
#pragma unroll
    for (int ni = 0; ni < 4; ++ni) {
      const int col = col0 + wx * 64 + ni * 16 + mrow;
      const int cl = col & 1023;
      const float bvl = bias[cl];
      f32x4 v = acc[mi][ni];
      if (part == 0) {
#pragma unroll
        for (int r = 0; r < 4; ++r)
          Qw[(size_t)(rowb + r) * 1024 + cl] = f2bf(v[r] + bvl);
      } else if (part == 1) {
#pragma unroll
        for (int r = 0; r < 4; ++r)
          Kw[(size_t)(rowb + r) * 1024 + cl] = f2bf(v[r] + bvl);
      } else {
        const int bb = rowb >> 11;
        const int ss = rowb & 2047;
        bf16x4 pk;
#pragma unroll
        for (int r = 0; r < 4; ++r) pk[r] = f2bf(v[r] + bvl);
        *(bf16x4*)(Vt + (size_t)bb * 2097152 + (size_t)cl * 2048 + ss) = pk;
      }
    }
  }
}

// ---------------------------------------------------------------------------
// MFMA cross-head conv1d (KS=3, zero pad) + softmax over key axis, in place.
// Round-6 kernel; writes UNNORMALIZED exp(x-M), emits 1/l to Lb (PV epilogue
// applies it). q0 = stripe base (round 11: scores/conv interleaved per
// 1024-q stripe for L3 residency). One block per q: 512 thr = 8 waves.
// conv_b skipped: constant along softmax (k) axis -> cancels exactly.
// ---------------------------------------------------------------------------
__global__ __launch_bounds__(512, 2) void conv_softmax(
    u16* __restrict__ SC, const float* __restrict__ cw, float* __restrict__ Lb,
    int q0) {
  __shared__ alignas(16) u16 rawT[1026 * 24];  // 49.3 KB
  __shared__ float redA[8][16];
  __shared__ float redB[8][16];

  const int tid = threadIdx.x;
  const int lane = tid & 63;
  const int wv = tid >> 6;
  const int q = blockIdx.x + q0;
  const int n = lane & 15;     // MFMA N-index = k-position within tile
  const int quad = lane >> 4;

  // A-frags (conv weights): lane's M-row h = n; kdim = quad*8+j -> (i,d)
  short8 a1, a2;
#pragma unroll
  for (int j = 0; j < 8; ++j) {
    const int kd = quad * 8 + j;
    const int i = kd & 15, d = kd >> 4;
    a1[j] = (short)f2bf(cw[n * 48 + i * 3 + d]);
    a2[j] = (quad < 2) ? (short)f2bf(cw[n * 48 + kd * 3 + 2]) : (short)0;
  }

  f32x4 acc[16];
#pragma unroll
  for (int ai = 0; ai < 16; ++ai) acc[ai] = f32x4{0.f, 0.f, 0.f, 0.f};

  for (int s = 0; s < 2; ++s) {
    if (s) __syncthreads();  // all reads of previous segment done
    const int segk = s * 1024;
    {  // transpose-load segment into rawT[k-local+1][h]
      const int h = tid & 15, kc = tid >> 4;  // kc in [0,32)
#pragma unroll
      for (int j = 0; j < 4; ++j) {
        const int kb = kc * 32 + j * 8;
        ushort8 v = *(const ushort8*)&SC[((size_t)h * 2048 + q) * 2048 + segk + kb];
#pragma unroll
        for (int e0 = 0; e0 < 8; ++e0) {
          const int e = (e0 + h) & 7;  // rotation to spread write banks
          rawT[(kb + e + 1) * 24 + h] = v[e];
        }
      }
      if (tid < 32) {  // halo rows: k = segk-1 (row 0) and segk+1024 (row 1025)
        const int h2 = tid & 15;
        const int top = tid >> 4;
        const int k = segk + (top ? 1024 : -1);
        u16 val = 0;
        if ((unsigned)k < 2048u) val = SC[((size_t)h2 * 2048 + q) * 2048 + k];
        rawT[(top ? 1025 : 0) * 24 + h2] = val;
      }
    }
    __syncthreads();

#pragma unroll
    for (int tt = 0; tt < 8; ++tt) {
      const int k0l = (wv * 8 + tt) * 16;  // local k of tile start
      const short8 b1 = *(const short8*)&rawT[(k0l + n + (quad >> 1)) * 24 + (quad & 1) * 8];
      const short8 b2 = *(const short8*)&rawT[(k0l + n + 2) * 24 + (quad & 1) * 8];
      const int ai = s * 8 + tt;
      acc[ai] = __builtin_amdgcn_mfma_f32_16x16x32_bf16(a1, b1, acc[ai], 0, 0, 0);
      acc[ai] = __builtin_amdgcn_mfma_f32_16x16x32_bf16(a2, b2, acc[ai], 0, 0, 0);
    }
  }

  // ---- softmax over k per head (head = quad*4 + r) ----
  float fm[4];
#pragma unroll
  for (int r = 0; r < 4; ++r) fm[r] = -3e38f;
#pragma unroll
  for (int ai = 0; ai < 16; ++ai)
#pragma unroll
    for (int r = 0; r < 4; ++r) fm[r] = fmaxf(fm[r], acc[ai][r]);
#pragma unroll
  for (int off = 1; off < 16; off <<= 1)
#pragma unroll
    for (int r = 0; r < 4; ++r) fm[r] = fmaxf(fm[r], __shfl_xor(fm[r], off));
  if (n == 0)
#pragma unroll
    for (int r = 0; r < 4; ++r) redA[wv][quad * 4 + r] = fm[r];
  __syncthreads();
#pragma unroll
  for (int r = 0; r < 4; ++r) {
    float m = redA[0][quad * 4 + r];
#pragma unroll
    for (int w = 1; w < 8; ++w) m = fmaxf(m, redA[w][quad * 4 + r]);
    fm[r] = m;
  }
  float fs[4] = {0.f, 0.f, 0.f, 0.f};
#pragma unroll
  for (int ai = 0; ai < 16; ++ai)
#pragma unroll
    for (int r = 0; r < 4; ++r) {
      acc[ai][r] = __expf(acc[ai][r] - fm[r]);
      fs[r] += acc[ai][r];
    }
#pragma unroll
  for (int off = 1; off < 16; off <<= 1)
#pragma unroll
    for (int r = 0; r < 4; ++r) fs[r] += __shfl_xor(fs[r], off);
  if (n == 0)
#pragma unroll
    for (int r = 0; r < 4; ++r) redB[wv][quad * 4 + r] = fs[r];
  __syncthreads();
  // 1/l -> Lb (normalization applied in PV epilogue)
  if (wv == 0 && n == 0) {
#pragma unroll
    for (int r = 0; r < 4; ++r) {
      float sum = 0.f;
#pragma unroll
      for (int w = 0; w < 8; ++w) sum += redB[w][quad * 4 + r];
      Lb[(size_t)(quad * 4 + r) * 2048 + q] = 1.f / sum;
    }
  }

  // ---- write back unnormalized exp (bf16, in place) ----
#pragma unroll
  for (int ai = 0; ai < 16; ++ai) {
    const int k0 = (ai >> 3) * 1024 + ((ai & 7) + wv * 8) * 16;
#pragma unroll
    for (int r = 0; r < 4; ++r) {
      const int h = quad * 4 + r;
      SC[((size_t)h * 2048 + q) * 2048 + k0 + n] = f2bf(acc[ai][r]);
    }
  }
}

// Diagnostic: fill f32 output with 2000.0 (ws-too-small marker).
__global__ void fill_diag(float* out, int n) {
  int i = blockIdx.x * 256 + threadIdx.x;
  if (i < n) out[i] = 2000.0f;
}

extern "C" void kernel_launch(void* const* d_in, const int* in_sizes, int n_in,
                              void* d_out, int out_size, void* d_ws, size_t ws_size,
                              hipStream_t stream) {
  const float* query = (const float*)d_in[0];
  const float* Wq = (const float*)d_in[1];
  const float* bq = (const float*)d_in[2];
  const float* Wk = (const float*)d_in[3];
  const float* bk = (const float*)d_in[4];
  const float* Wv = (const float*)d_in[5];
  const float* bv = (const float*)d_in[6];
  const float* Wo = (const float*)d_in[7];
  const float* bo = (const float*)d_in[8];
  const float* cw = (const float*)d_in[9];
  // d_in[10] (conv_b) intentionally unused: cancels in softmax.

  const size_t SE = (size_t)4096 * 1024;  // B*S*E elems
  const size_t WE = (size_t)1024 * 1024;  // E*E elems
  const size_t SCE = (size_t)16 * 2048 * 2048;  // per-batch scores elems
  const size_t fixedB = ((SE + 4 * WE) + 4 * SE) * sizeof(u16);  // 48 MiB
  const size_t LBB = (size_t)16 * 2048 * sizeof(float);          // 128 KiB
  if (ws_size < fixedB + SCE * sizeof(u16) + LBB) {
    fill_diag<<<dim3((out_size + 255) / 256), dim3(256), 0, stream>>>(
        (float*)d_out, out_size);
    return;
  }

  u16* ws = (u16*)d_ws;
  u16* Qb = ws;              // bf16 query [b][s][e]
  u16* Wqb = Qb + SE;        // bf16 weights (contiguous: Wq|Wk|Wv|Wo)
  u16* Wkb = Wqb + WE;
  u16* Wvb = Wkb + WE;
  u16* Wob = Wvb + WE;
  u16* Qw = Wob + WE;        // [b][s][e]
  u16* Kw = Qw + SE;         // [b][s][e]
  u16* Vt = Kw + SE;         // [b][e][s] transposed V
  u16* At = Vt + SE;         // attention output [b][s][e] (bf16)
  u16* SC = At + SE;         // scores (one batch) [h][q][k]
  float* Lb = (float*)(SC + SCE);  // inverse softmax sums [h][q]

  dim3 blk(256);
  cvt_all<<<dim3(4096), blk, 0, stream>>>(query, Wq, Wk, Wv, Wo, Qb);

  // Fused Q/K/V projection: B rows = Wqb|Wkb|Wvb (contiguous, 3072 x 1024)
  gemm_qkv<<<dim3(24, 32, 1), blk, 0, stream>>>(
      Qb, Wqb, bq, bk, bv, Qw, Kw, Vt);

  constexpr int QS = 1024;  // q-stripe (L3 live set = 64 MB raw + P <= 198 MB)
  for (int b = 0; b < 2; ++b) {
    const size_t bQK = (size_t)b * 2097152;
    for (int q0 = 0; q0 < 2048; q0 += QS) {
      // raw scores stripe: M=QS, N=2048, K=64 (BK=64, single stage)
      gemm_nt<128, 128, 64, false, false, false, false>
          <<<dim3(16, QS / 128, 16), blk, 0, stream>>>(
              Qw + bQK + (size_t)q0 * 1024, Kw + bQK, nullptr,
              SC + (size_t)q0 * 2048, nullptr,
              64, 1024, 1024, 2048, 0.125f, 64LL, 64LL, 4194304LL);
      // conv + softmax on the stripe (raw stripe is L3-hot)
      conv_softmax<<<dim3(QS), dim3(512), 0, stream>>>(SC, cw, Lb, q0);
    }
    // PV: M=2048 (q), N=64 (d), K=2048 per head; epilogue applies 1/l.
    // P is fully L3-resident at this point (134 MB < 256 MB).
    gemm_nt<64, 64, 32, false, false, false, true>
        <<<dim3(1, 32, 16), blk, 0, stream>>>(
            SC, Vt + bQK, nullptr, At + bQK, Lb,
            2048, 2048, 2048, 1024, 1.f, 4194304LL, 131072LL, 64LL);
  }

  // output projection -> f32 d_out
  gemm_nt<128, 128, 32, false, true, true, false><<<dim3(8, 32, 1), blk, 0, stream>>>(
      At, Wob, bo, d_out, nullptr, 1024, 1024, 1024, 1024, 1.f, 0, 0, 0);
}

// Round 12
// 428.682 us; speedup vs baseline: 1.1375x; 1.1375x over previous
//
#include <hip/hip_runtime.h>

typedef unsigned short u16;
typedef short short8 __attribute__((ext_vector_type(8)));
typedef unsigned short ushort8 __attribute__((ext_vector_type(8)));
typedef unsigned short bf16x4 __attribute__((ext_vector_type(4)));
typedef float f32x4 __attribute__((ext_vector_type(4)));

#define DEVINL __device__ __forceinline__

DEVINL float bf2f(u16 u) {
  unsigned int x = ((unsigned int)u) << 16;
  return __builtin_bit_cast(float, x);
}
DEVINL u16 f2bf(float f) {
  unsigned int x = __builtin_bit_cast(unsigned int, f);
  x += 0x7FFFu + ((x >> 16) & 1u);  // RNE
  return (u16)(x >> 16);
}

// Problem constants: B=2, S=2048, E=1024, H=16, DH=64
// Inputs float32; big operands converted once to bf16; MFMA internally;
// final output written as float32.
// Round-12: q-striping reverted (launch overhead > L3 gain, r11); BK=64 in
// qkv/PV/out-proj to halve K-loop barrier pairs.

// ---------------------------------------------------------------------------
// Fused f32 -> bf16 conversion of query + 4 weight matrices.
// ---------------------------------------------------------------------------
__global__ __launch_bounds__(256) void cvt_all(
    const float* __restrict__ q, const float* __restrict__ wq,
    const float* __restrict__ wk, const float* __restrict__ wv,
    const float* __restrict__ wo, u16* __restrict__ out) {
  int i = blockIdx.x * 256 + threadIdx.x;  // < 1048576
  const float* src;
  size_t off8;
  if (i < 524288) { src = q;  off8 = i; }
  else if (i < 655360) { src = wq; off8 = i - 524288; }
  else if (i < 786432) { src = wk; off8 = i - 655360; }
  else if (i < 917504) { src = wv; off8 = i - 786432; }
  else { src = wo; off8 = i - 917504; }
  f32x4 a = ((const f32x4*)src)[2 * off8];
  f32x4 b = ((const f32x4*)src)[2 * off8 + 1];
  ushort8 o;
#pragma unroll
  for (int e = 0; e < 4; ++e) o[e] = f2bf(a[e]);
#pragma unroll
  for (int e = 0; e < 4; ++e) o[4 + e] = f2bf(b[e]);
  ((ushort8*)out)[i] = o;
}

// ---------------------------------------------------------------------------
// NT GEMM (bf16 in via MFMA): C[i,j] = scale * sum_k A[i,k]*B[j,k] (+ bias[j])
// BK: K-tile (32 or 64). RSCALE: multiply row i of batch z by rsc[z*2048+i].
// ---------------------------------------------------------------------------
template <int BM, int BN, int BK, bool TRANSV, bool HASBIAS, bool OUTF32,
          bool RSCALE>
__global__ __launch_bounds__(256) void gemm_nt(
    const u16* __restrict__ A, const u16* __restrict__ Bm,
    const float* __restrict__ bias, void* __restrict__ C,
    const float* __restrict__ rsc,
    int K, int lda, int ldb, int ldc, float scale,
    long long sAh, long long sBh, long long sCh) {
  constexpr int LDSS = BK + 8;       // padded LDS row stride (u16)
  constexpr int KC8 = BK / 8;        // 8-elem groups per row
  constexpr int KSH = (BK == 32) ? 2 : 3;
  constexpr int WM = BM / 2, WN = BN / 2, FM = WM / 16, FN = WN / 16;
  constexpr int AIN = BM * KC8 / 256;
  constexpr int BIN = BN * KC8 / 256;

  __shared__ alignas(16) u16 As[BM * LDSS];
  __shared__ alignas(16) u16 Bs[BN * LDSS];

  const int tid = threadIdx.x;
  const int lane = tid & 63;
  const int wv = tid >> 6;
  const int wy = wv >> 1, wx = wv & 1;
  const int quad = lane >> 4, mrow = lane & 15;

  const int z = blockIdx.z;
  const u16* Ap = A + z * sAh;
  const u16* Bp = Bm + z * sBh;
  u16* Cp = (u16*)C + z * sCh;
  float* Cf = (float*)C + z * sCh;

  const int row0 = blockIdx.y * BM;
  const int col0 = blockIdx.x * BN;

  f32x4 acc[FM][FN];
#pragma unroll
  for (int i = 0; i < FM; ++i)
#pragma unroll
    for (int j = 0; j < FN; ++j) acc[i][j] = f32x4{0.f, 0.f, 0.f, 0.f};

  for (int k0 = 0; k0 < K; k0 += BK) {
    ushort8 ta[AIN], tb[BIN];
#pragma unroll
    for (int r = 0; r < AIN; ++r) {
      int idx = r * 256 + tid;
      int row = idx >> KSH, ch = idx & (KC8 - 1);
      ta[r] = *(const ushort8*)(Ap + (size_t)(row0 + row) * lda + k0 + ch * 8);
    }
#pragma unroll
    for (int r = 0; r < BIN; ++r) {
      int idx = r * 256 + tid;
      int row = idx >> KSH, ch = idx & (KC8 - 1);
      tb[r] = *(const ushort8*)(Bp + (size_t)(col0 + row) * ldb + k0 + ch * 8);
    }
    __syncthreads();  // previous iteration's LDS reads done
#pragma unroll
    for (int r = 0; r < AIN; ++r) {
      int idx = r * 256 + tid;
      int row = idx >> KSH, ch = idx & (KC8 - 1);
      *(ushort8*)&As[row * LDSS + ch * 8] = ta[r];
    }
#pragma unroll
    for (int r = 0; r < BIN; ++r) {
      int idx = r * 256 + tid;
      int row = idx >> KSH, ch = idx & (KC8 - 1);
      *(ushort8*)&Bs[row * LDSS + ch * 8] = tb[r];
    }
    __syncthreads();

#pragma unroll
    for (int ks = 0; ks < BK / 32; ++ks) {
      short8 af[FM], bfr[FN];
#pragma unroll
      for (int mi = 0; mi < FM; ++mi)
        af[mi] = *(const short8*)&As[(wy * WM + mi * 16 + mrow) * LDSS + ks * 32 + quad * 8];
#pragma unroll
      for (int ni = 0; ni < FN; ++ni)
        bfr[ni] = *(const short8*)&Bs[(wx * WN + ni * 16 + mrow) * LDSS + ks * 32 + quad * 8];
#pragma unroll
      for (int mi = 0; mi < FM; ++mi)
#pragma unroll
        for (int ni = 0; ni < FN; ++ni)
          acc[mi][ni] = __builtin_amdgcn_mfma_f32_16x16x32_bf16(
              af[mi], bfr[ni], acc[mi][ni], 0, 0, 0);
    }
  }

  // Epilogue. C/D layout: col = lane&15, row = quad*4 + r  [m89/m91 verified]
#pragma unroll
  for (int mi = 0; mi < FM; ++mi) {
    const int rowb = row0 + wy * WM + mi * 16 + quad * 4;
#pragma unroll
    for (int ni = 0; ni < FN; ++ni) {
      const int col = col0 + wx * WN + ni * 16 + mrow;
      float bv = 0.f;
      if (HASBIAS) bv = bias[col];
      f32x4 v = acc[mi][ni];
      if (OUTF32) {
#pragma unroll
        for (int r = 0; r < 4; ++r)
          Cf[(size_t)(rowb + r) * ldc + col] = v[r] * scale + bv;
      } else if (!TRANSV) {
#pragma unroll
        for (int r = 0; r < 4; ++r) {
          float rs = 1.f;
          if (RSCALE) rs = rsc[(size_t)z * 2048 + rowb + r];
          Cp[(size_t)(rowb + r) * ldc + col] = f2bf(v[r] * scale * rs + bv);
        }
      } else {
        // Ct[b][col][s], per-batch stride E*S = 2097152
        const int bb = rowb >> 11;
        const int ss = rowb & 2047;
        bf16x4 pk;
#pragma unroll
        for (int r = 0; r < 4; ++r) pk[r] = f2bf(v[r] * scale + bv);
        *(bf16x4*)(Cp + (size_t)bb * 2097152 + (size_t)col * 2048 + ss) = pk;
      }
    }
  }
}

// ---------------------------------------------------------------------------
// Fused QKV projection: A = Qb [4096 x 1024], B = Wq|Wk|Wv rows [3072 x 1024].
// col part (block-uniform, BN=128): 0 -> Qw, 1 -> Kw, 2 -> Vt (transposed
// store Vt[b][e][s]). BK=64 (16 K-iters), BM=BN=128.
// ---------------------------------------------------------------------------
__global__ __launch_bounds__(256) void gemm_qkv(
    const u16* __restrict__ A, const u16* __restrict__ Bm,
    const float* __restrict__ bq, const float* __restrict__ bk,
    const float* __restrict__ bv,
    u16* __restrict__ Qw, u16* __restrict__ Kw, u16* __restrict__ Vt) {
  constexpr int LDSS = 72;
  __shared__ alignas(16) u16 As[128 * LDSS];
  __shared__ alignas(16) u16 Bs[128 * LDSS];

  const int tid = threadIdx.x;
  const int lane = tid & 63;
  const int wv = tid >> 6;
  const int wy = wv >> 1, wx = wv & 1;
  const int quad = lane >> 4, mrow = lane & 15;

  const int row0 = blockIdx.y * 128;
  const int col0 = blockIdx.x * 128;

  f32x4 acc[4][4];
#pragma unroll
  for (int i = 0; i < 4; ++i)
#pragma unroll
    for (int j = 0; j < 4; ++j) acc[i][j] = f32x4{0.f, 0.f, 0.f, 0.f};

  for (int k0 = 0; k0 < 1024; k0 += 64) {
    ushort8 ta[4], tb[4];
#pragma unroll
    for (int r = 0; r < 4; ++r) {
      int idx = r * 256 + tid;
      int row = idx >> 3, ch = idx & 7;
      ta[r] = *(const ushort8*)(A + (size_t)(row0 + row) * 1024 + k0 + ch * 8);
      tb[r] = *(const ushort8*)(Bm + (size_t)(col0 + row) * 1024 + k0 + ch * 8);
    }
    __syncthreads();
#pragma unroll
    for (int r = 0; r < 4; ++r) {
      int idx = r * 256 + tid;
      int row = idx >> 3, ch = idx & 7;
      *(ushort8*)&As[row * LDSS + ch * 8] = ta[r];
      *(ushort8*)&Bs[row * LDSS + ch * 8] = tb[r];
    }
    __syncthreads();

#pragma unroll
    for (int ks = 0; ks < 2; ++ks) {
      short8 af[4], bfr[4];
#pragma unroll
      for (int mi = 0; mi < 4; ++mi)
        af[mi] = *(const short8*)&As[(wy * 64 + mi * 16 + mrow) * LDSS + ks * 32 + quad * 8];
#pragma unroll
      for (int ni = 0; ni < 4; ++ni)
        bfr[ni] = *(const short8*)&Bs[(wx * 64 + ni * 16 + mrow) * LDSS + ks * 32 + quad * 8];
#pragma unroll
      for (int mi = 0; mi < 4; ++mi)
#pragma unroll
        for (int ni = 0; ni < 4; ++ni)
          acc[mi][ni] = __builtin_amdgcn_mfma_f32_16x16x32_bf16(
              af[mi], bfr[ni], acc[mi][ni], 0, 0, 0);
    }
  }

  const int part = col0 >> 10;  // 0:Q 1:K 2:V (block-uniform)
  const float* bias = (part == 0) ? bq : (part == 1) ? bk : bv;
#pragma unroll
  for (int mi = 0; mi < 4; ++mi) {
    const int rowb = row0 + wy * 64 + mi * 16 + quad * 4;
#pragma unroll
    for (int ni = 0; ni < 4; ++ni) {
      const int col = col0 + wx * 64 + ni * 16 + mrow;
      const int cl = col & 1023;
      const float bvl = bias[cl];
      f32x4 v = acc[mi][ni];
      if (part == 0) {
#pragma unroll
        for (int r = 0; r < 4; ++r)
          Qw[(size_t)(rowb + r) * 1024 + cl] = f2bf(v[r] + bvl);
      } else if (part == 1) {
#pragma unroll
        for (int r = 0; r < 4; ++r)
          Kw[(size_t)(rowb + r) * 1024 + cl] = f2bf(v[r] + bvl);
      } else {
        const int bb = rowb >> 11;
        const int ss = rowb & 2047;
        bf16x4 pk;
#pragma unroll
        for (int r = 0; r < 4; ++r) pk[r] = f2bf(v[r] + bvl);
        *(bf16x4*)(Vt + (size_t)bb * 2097152 + (size_t)cl * 2048 + ss) = pk;
      }
    }
  }
}

// ---------------------------------------------------------------------------
// MFMA cross-head conv1d (KS=3, zero pad) + softmax over key axis, in place.
// Writes UNNORMALIZED exp(x-M), emits 1/l to Lb (PV epilogue applies it).
// LDS rawT[k][h] stride 24 (conflict-free b128 reads), 2 segments of 1024
// (+2 halo rows). One block per q: 512 thr = 8 waves. Occupancy is
// register-bound (acc[16]=64 AGPR + ~60 VGPR -> 2 blocks/CU); k-split would
// break softmax, so this is the structural shape.
// conv_b skipped: constant along softmax (k) axis -> cancels exactly.
// ---------------------------------------------------------------------------
__global__ __launch_bounds__(512, 2) void conv_softmax(
    u16* __restrict__ SC, const float* __restrict__ cw, float* __restrict__ Lb) {
  __shared__ alignas(16) u16 rawT[1026 * 24];  // 49.3 KB
  __shared__ float redA[8][16];
  __shared__ float redB[8][16];

  const int tid = threadIdx.x;
  const int lane = tid & 63;
  const int wv = tid >> 6;
  const int q = blockIdx.x;
  const int n = lane & 15;     // MFMA N-index = k-position within tile
  const int quad = lane >> 4;

  // A-frags (conv weights): lane's M-row h = n; kdim = quad*8+j -> (i,d)
  short8 a1, a2;
#pragma unroll
  for (int j = 0; j < 8; ++j) {
    const int kd = quad * 8 + j;
    const int i = kd & 15, d = kd >> 4;
    a1[j] = (short)f2bf(cw[n * 48 + i * 3 + d]);
    a2[j] = (quad < 2) ? (short)f2bf(cw[n * 48 + kd * 3 + 2]) : (short)0;
  }

  f32x4 acc[16];
#pragma unroll
  for (int ai = 0; ai < 16; ++ai) acc[ai] = f32x4{0.f, 0.f, 0.f, 0.f};

  for (int s = 0; s < 2; ++s) {
    if (s) __syncthreads();  // all reads of previous segment done
    const int segk = s * 1024;
    {  // transpose-load segment into rawT[k-local+1][h]
      const int h = tid & 15, kc = tid >> 4;  // kc in [0,32)
#pragma unroll
      for (int j = 0; j < 4; ++j) {
        const int kb = kc * 32 + j * 8;
        ushort8 v = *(const ushort8*)&SC[((size_t)h * 2048 + q) * 2048 + segk + kb];
#pragma unroll
        for (int e0 = 0; e0 < 8; ++e0) {
          const int e = (e0 + h) & 7;  // rotation to spread write banks
          rawT[(kb + e + 1) * 24 + h] = v[e];
        }
      }
      if (tid < 32) {  // halo rows: k = segk-1 (row 0) and segk+1024 (row 1025)
        const int h2 = tid & 15;
        const int top = tid >> 4;
        const int k = segk + (top ? 1024 : -1);
        u16 val = 0;
        if ((unsigned)k < 2048u) val = SC[((size_t)h2 * 2048 + q) * 2048 + k];
        rawT[(top ? 1025 : 0) * 24 + h2] = val;
      }
    }
    __syncthreads();

#pragma unroll
    for (int tt = 0; tt < 8; ++tt) {
      const int k0l = (wv * 8 + tt) * 16;  // local k of tile start
      const short8 b1 = *(const short8*)&rawT[(k0l + n + (quad >> 1)) * 24 + (quad & 1) * 8];
      const short8 b2 = *(const short8*)&rawT[(k0l + n + 2) * 24 + (quad & 1) * 8];
      const int ai = s * 8 + tt;
      acc[ai] = __builtin_amdgcn_mfma_f32_16x16x32_bf16(a1, b1, acc[ai], 0, 0, 0);
      acc[ai] = __builtin_amdgcn_mfma_f32_16x16x32_bf16(a2, b2, acc[ai], 0, 0, 0);
    }
  }

  // ---- softmax over k per head (head = quad*4 + r) ----
  float fm[4];
#pragma unroll
  for (int r = 0; r < 4; ++r) fm[r] = -3e38f;
#pragma unroll
  for (int ai = 0; ai < 16; ++ai)
#pragma unroll
    for (int r = 0; r < 4; ++r) fm[r] = fmaxf(fm[r], acc[ai][r]);
#pragma unroll
  for (int off = 1; off < 16; off <<= 1)
#pragma unroll
    for (int r = 0; r < 4; ++r) fm[r] = fmaxf(fm[r], __shfl_xor(fm[r], off));
  if (n == 0)
#pragma unroll
    for (int r = 0; r < 4; ++r) redA[wv][quad * 4 + r] = fm[r];
  __syncthreads();
#pragma unroll
  for (int r = 0; r < 4; ++r) {
    float m = redA[0][quad * 4 + r];
#pragma unroll
    for (int w = 1; w < 8; ++w) m = fmaxf(m, redA[w][quad * 4 + r]);
    fm[r] = m;
  }
  float fs[4] = {0.f, 0.f, 0.f, 0.f};
#pragma unroll
  for (int ai = 0; ai < 16; ++ai)
#pragma unroll
    for (int r = 0; r < 4; ++r) {
      acc[ai][r] = __expf(acc[ai][r] - fm[r]);
      fs[r] += acc[ai][r];
    }
#pragma unroll
  for (int off = 1; off < 16; off <<= 1)
#pragma unroll
    for (int r = 0; r < 4; ++r) fs[r] += __shfl_xor(fs[r], off);
  if (n == 0)
#pragma unroll
    for (int r = 0; r < 4; ++r) redB[wv][quad * 4 + r] = fs[r];
  __syncthreads();
  // 1/l -> Lb (normalization applied in PV epilogue)
  if (wv == 0 && n == 0) {
#pragma unroll
    for (int r = 0; r < 4; ++r) {
      float sum = 0.f;
#pragma unroll
      for (int w = 0; w < 8; ++w) sum += redB[w][quad * 4 + r];
      Lb[(size_t)(quad * 4 + r) * 2048 + q] = 1.f / sum;
    }
  }

  // ---- write back unnormalized exp (bf16, in place) ----
#pragma unroll
  for (int ai = 0; ai < 16; ++ai) {
    const int k0 = (ai >> 3) * 1024 + ((ai & 7) + wv * 8) * 16;
#pragma unroll
    for (int r = 0; r < 4; ++r) {
      const int h = quad * 4 + r;
      SC[((size_t)h * 2048 + q) * 2048 + k0 + n] = f2bf(acc[ai][r]);
    }
  }
}

// Diagnostic: fill f32 output with 2000.0 (ws-too-small marker).
__global__ void fill_diag(float* out, int n) {
  int i = blockIdx.x * 256 + threadIdx.x;
  if (i < n) out[i] = 2000.0f;
}

extern "C" void kernel_launch(void* const* d_in, const int* in_sizes, int n_in,
                              void* d_out, int out_size, void* d_ws, size_t ws_size,
                              hipStream_t stream) {
  const float* query = (const float*)d_in[0];
  const float* Wq = (const float*)d_in[1];
  const float* bq = (const float*)d_in[2];
  const float* Wk = (const float*)d_in[3];
  const float* bk = (const float*)d_in[4];
  const float* Wv = (const float*)d_in[5];
  const float* bv = (const float*)d_in[6];
  const float* Wo = (const float*)d_in[7];
  const float* bo = (const float*)d_in[8];
  const float* cw = (const float*)d_in[9];
  // d_in[10] (conv_b) intentionally unused: cancels in softmax.

  const size_t SE = (size_t)4096 * 1024;  // B*S*E elems
  const size_t WE = (size_t)1024 * 1024;  // E*E elems
  const size_t SCE = (size_t)16 * 2048 * 2048;  // per-batch scores elems
  const size_t fixedB = ((SE + 4 * WE) + 4 * SE) * sizeof(u16);  // 48 MiB
  const size_t LBB = (size_t)16 * 2048 * sizeof(float);          // 128 KiB
  if (ws_size < fixedB + SCE * sizeof(u16) + LBB) {
    fill_diag<<<dim3((out_size + 255) / 256), dim3(256), 0, stream>>>(
        (float*)d_out, out_size);
    return;
  }

  u16* ws = (u16*)d_ws;
  u16* Qb = ws;              // bf16 query [b][s][e]
  u16* Wqb = Qb + SE;        // bf16 weights (contiguous: Wq|Wk|Wv|Wo)
  u16* Wkb = Wqb + WE;
  u16* Wvb = Wkb + WE;
  u16* Wob = Wvb + WE;
  u16* Qw = Wob + WE;        // [b][s][e]
  u16* Kw = Qw + SE;         // [b][s][e]
  u16* Vt = Kw + SE;         // [b][e][s] transposed V
  u16* At = Vt + SE;         // attention output [b][s][e] (bf16)
  u16* SC = At + SE;         // scores (one batch) [h][q][k]
  float* Lb = (float*)(SC + SCE);  // inverse softmax sums [h][q]

  dim3 blk(256);
  cvt_all<<<dim3(4096), blk, 0, stream>>>(query, Wq, Wk, Wv, Wo, Qb);

  // Fused Q/K/V projection (BK=64): B rows = Wqb|Wkb|Wvb (3072 x 1024)
  gemm_qkv<<<dim3(24, 32, 1), blk, 0, stream>>>(
      Qb, Wqb, bq, bk, bv, Qw, Kw, Vt);

  for (int b = 0; b < 2; ++b) {
    const size_t bQK = (size_t)b * 2097152;
    // raw scores = Q Kh^T / 8 per head: M=N=2048, K=64 (BK=64, single stage)
    gemm_nt<128, 128, 64, false, false, false, false>
        <<<dim3(16, 16, 16), blk, 0, stream>>>(
            Qw + bQK, Kw + bQK, nullptr, SC, nullptr,
            64, 1024, 1024, 2048, 0.125f, 64LL, 64LL, 4194304LL);
    // conv + softmax (unnormalized P + 1/l into Lb)
    conv_softmax<<<dim3(2048), dim3(512), 0, stream>>>(SC, cw, Lb);
    // PV: M=2048 (q), N=64 (d), K=2048 per head (BK=64); epilogue applies 1/l
    gemm_nt<64, 64, 64, false, false, false, true>
        <<<dim3(1, 32, 16), blk, 0, stream>>>(
            SC, Vt + bQK, nullptr, At + bQK, Lb,
            2048, 2048, 2048, 1024, 1.f, 4194304LL, 131072LL, 64LL);
  }

  // output projection (BK=64) -> f32 d_out
  gemm_nt<128, 128, 64, false, true, true, false><<<dim3(8, 32, 1), blk, 0, stream>>>(
      At, Wob, bo, d_out, nullptr, 1024, 1024, 1024, 1024, 1.f, 0, 0, 0);
}